// Round 4
// baseline (49.606 us; speedup 1.0000x reference)
//
#include <hip/hip_runtime.h>
#include <hip/hip_bf16.h>

#define BB 4
#define SS 2048
#define DD 16
#define KK 204      // max(1, int(2048*0.1))
#define JSPLIT 8

typedef __attribute__((ext_vector_type(8))) short short8;
typedef __attribute__((ext_vector_type(4))) float f32x4;

__device__ inline short f2bf(float x) {
  __hip_bfloat16 b = __float2bfloat16(x);
  return *reinterpret_cast<short*>(&b);
}

// ---------------- Kernel A: scores + q_part ----------------
__global__ void __launch_bounds__(256) score_q_kernel(
    const float* __restrict__ full, const float* __restrict__ sw1,
    const float* __restrict__ sb1, const float* __restrict__ sw2,
    const float* __restrict__ sb2, const float* __restrict__ mw1,
    float* __restrict__ scores, float* __restrict__ qpart) {
  int idx = blockIdx.x * blockDim.x + threadIdx.x;  // b*SS + s
  if (idx >= BB * SS) return;
  float x[16];
  const float* xp = full + idx * DD;
#pragma unroll
  for (int i = 0; i < 16; i++) x[i] = xp[i];

  float sc = sb2[0];
#pragma unroll
  for (int n = 0; n < 32; n++) {
    float a = sb1[n];
#pragma unroll
    for (int k = 0; k < 16; k++) a += x[k] * sw1[k * 32 + n];
    a = fmaxf(a, 0.f);
    sc += a * sw2[n];
  }
  scores[idx] = sc;

#pragma unroll
  for (int n = 0; n < 64; n++) {
    float a = 0.f;
#pragma unroll
    for (int k = 0; k < 16; k++) a += x[k] * mw1[k * 64 + n];  // w_q = mw1[:16]
    qpart[idx * 64 + n] = a;
  }
}

// ---- Kernel B: fused per-batch top-204 radix select + kvb compute ----
// key = monotone(score)<<11 | (2047-i): larger key = larger value, then
// smaller index; unique keys -> "key >= K*" selects exactly KK items,
// identical semantics to jax top_k. 4 passes of 11 bits (44 >= 43 key bits).
// After selection, the same block computes kvb[b][j][:] = x_sel @ (wk+wv)+mb1.
__global__ void __launch_bounds__(256) topk_kvb_kernel(
    const float* __restrict__ scores, const float* __restrict__ full,
    const float* __restrict__ mw1, const float* __restrict__ mb1,
    float* __restrict__ kvb) {
  int b = blockIdx.x;
  int t = threadIdx.x;
  int lane = t & 63, w = t >> 6;

  __shared__ int hist[2048];       // 8 KB
  __shared__ int wtot[4];
  __shared__ unsigned long long s_pfx;
  __shared__ int s_r;
  __shared__ int s_idx[KK];
  __shared__ float wsum[16 * 64];  // wk + wv, 4 KB

  // stage wsum (consumed after many barriers)
#pragma unroll
  for (int kk = 0; kk < 4; kk++) {
    int k = kk * 4 + w;
    wsum[k * 64 + lane] = mw1[(16 + k) * 64 + lane] + mw1[(32 + k) * 64 + lane];
  }

  unsigned long long key[8];
#pragma unroll
  for (int e = 0; e < 8; e++) {
    int i = t + e * 256;
    float f = scores[b * SS + i];
    unsigned u = __float_as_uint(f);
    u = (u & 0x80000000u) ? ~u : (u | 0x80000000u);  // order-preserving asc
    key[e] = ((unsigned long long)u << 11) | (unsigned)(SS - 1 - i);
  }
  if (t == 0) { s_pfx = 0ull; s_r = KK; }

#pragma unroll
  for (int pass = 0; pass < 4; pass++) {
    int s = 33 - pass * 11;
#pragma unroll
    for (int z = 0; z < 8; z++) hist[t + z * 256] = 0;
    __syncthreads();                       // hist zeroed; s_pfx/s_r visible
    unsigned long long pfx = s_pfx;
    int r = s_r;
#pragma unroll
    for (int e = 0; e < 8; e++) {
      if ((key[e] >> (s + 11)) == pfx)
        atomicAdd(&hist[(int)((key[e] >> s) & 0x7FF)], 1);
    }
    __syncthreads();
    // thread owns bins t*8 .. t*8+7; ls[i] = suffix sum within the 8
    int loc[8], ls[9];
#pragma unroll
    for (int i = 0; i < 8; i++) loc[i] = hist[t * 8 + i];
    ls[8] = 0;
#pragma unroll
    for (int i = 7; i >= 0; i--) ls[i] = ls[i + 1] + loc[i];
    int tot = ls[0];
    // wave inclusive suffix-scan of tot
    int incl = tot;
#pragma unroll
    for (int off = 1; off < 64; off <<= 1) {
      int o = __shfl_down(incl, off);
      incl += (lane + off < 64) ? o : 0;
    }
    if (lane == 0) wtot[w] = incl;  // wave total (suffix over whole wave)
    __syncthreads();
    int waveoff = 0;
    for (int ww = w + 1; ww < 4; ww++) waveoff += wtot[ww];
    int excl_thread = waveoff + (incl - tot);  // sum over threads > t
#pragma unroll
    for (int i = 0; i < 8; i++) {
      int sufs = ls[i] + excl_thread;
      int sufn = ls[i + 1] + excl_thread;
      if (sufs >= r && sufn < r) {          // exactly one (thread,bin) matches
        s_pfx = (pfx << 11) | (unsigned)(t * 8 + i);
        s_r = r - sufn;
      }
    }
    __syncthreads();
  }

  unsigned long long kstar = s_pfx;  // full 43-bit key of rank-KK item
  // deterministic compaction: write order sorted by (t, e)
  bool selm[8];
  int c = 0;
#pragma unroll
  for (int e = 0; e < 8; e++) {
    selm[e] = (key[e] >= kstar);
    c += selm[e] ? 1 : 0;
  }
  int p = c;  // wave inclusive prefix
#pragma unroll
  for (int off = 1; off < 64; off <<= 1) {
    int o = __shfl_up(p, off);
    p += (lane >= off) ? o : 0;
  }
  if (lane == 63) wtot[w] = p;
  __syncthreads();
  int base = 0;
  for (int ww = 0; ww < w; ww++) base += wtot[ww];
  int pos = base + p - c;
#pragma unroll
  for (int e = 0; e < 8; e++) {
    if (selm[e]) s_idx[pos++] = t + e * 256;
  }
  __syncthreads();

  // kvb: wave w handles j = w, w+4, ...
  float biasv = mb1[lane];
  for (int j = w; j < KK; j += 4) {
    const float* xp = full + (b * SS + s_idx[j]) * DD;
    f32x4 x0 = *(const f32x4*)(xp);
    f32x4 x1 = *(const f32x4*)(xp + 4);
    f32x4 x2 = *(const f32x4*)(xp + 8);
    f32x4 x3 = *(const f32x4*)(xp + 12);
    float a = biasv;
#pragma unroll
    for (int k = 0; k < 4; k++) a += x0[k] * wsum[k * 64 + lane];
#pragma unroll
    for (int k = 0; k < 4; k++) a += x1[k] * wsum[(4 + k) * 64 + lane];
#pragma unroll
    for (int k = 0; k < 4; k++) a += x2[k] * wsum[(8 + k) * 64 + lane];
#pragma unroll
    for (int k = 0; k < 4; k++) a += x3[k] * wsum[(12 + k) * 64 + lane];
    kvb[(b * KK + j) * 64 + lane] = a;
  }
}

// ---------------- Kernel D: main (MFMA bf16) ----------------
// Block = 8 waves, one m-tile of 16 (b,s) rows; wave w handles 26 j's.
// A frag (16x16x32 bf16): lane l holds A[m=l&15][k=8*(l>>4)+i], i=0..7.
// B frag:                 lane l holds B[k=8*(l>>4)+i][n=l&15].
// D frag (m89-verified):  lane l, reg r -> D[m=4*(l>>4)+r][n=l&15].
__global__ void __launch_bounds__(512) main_mfma_kernel(
    const float* __restrict__ qpart, const float* __restrict__ kvb,
    const float* __restrict__ mw2, const float* __restrict__ mb2,
    const float* __restrict__ mw3, const float* __restrict__ mb3,
    float* __restrict__ out) {
  int mtile = blockIdx.x;            // 0..511
  int bs_base = mtile * 16;
  int b = bs_base >> 11;
  int t = threadIdx.x;
  int w = t >> 6;
  int l = t & 63;
  int ml = l & 15;
  int g = l >> 4;

  f32x4 qv[2][2];
  {
    const float* qp = qpart + (bs_base + ml) * 64 + 8 * g;
    qv[0][0] = *(const f32x4*)(qp);
    qv[0][1] = *(const f32x4*)(qp + 4);
    qv[1][0] = *(const f32x4*)(qp + 32);
    qv[1][1] = *(const f32x4*)(qp + 36);
  }

  short8 bfrag[2][2];  // [ntile][khalf]
#pragma unroll
  for (int nt = 0; nt < 2; nt++)
#pragma unroll
    for (int kh = 0; kh < 2; kh++)
#pragma unroll
      for (int i = 0; i < 8; i++) {
        int k = kh * 32 + 8 * g + i;
        bfrag[nt][kh][i] = f2bf(mw2[k * 32 + nt * 16 + ml]);
      }

  f32x4 biasfrag[2];
#pragma unroll
  for (int nt = 0; nt < 2; nt++) {
    float bv = mb2[nt * 16 + ml];
    f32x4 bf;
    bf[0] = bv; bf[1] = bv; bf[2] = bv; bf[3] = bv;
    biasfrag[nt] = bf;
  }

  const f32x4 zero4 = {0.f, 0.f, 0.f, 0.f};
  float accs[2][4] = {};
  int jbeg = w * 26;
  int jend = jbeg + 26;
  if (jend > KK) jend = KK;
  const float* kvbb = kvb + b * KK * 64 + 8 * g;

#pragma unroll 2
  for (int j = jbeg; j < jend; j++) {
    const float* kp = kvbb + j * 64;
    f32x4 kvv[2][2];
    kvv[0][0] = *(const f32x4*)(kp);
    kvv[0][1] = *(const f32x4*)(kp + 4);
    kvv[1][0] = *(const f32x4*)(kp + 32);
    kvv[1][1] = *(const f32x4*)(kp + 36);

    short8 afrag[2];
#pragma unroll
    for (int kh = 0; kh < 2; kh++)
#pragma unroll
      for (int hf = 0; hf < 2; hf++) {
        f32x4 s = qv[kh][hf] + kvv[kh][hf];           // -> v_pk_add_f32
        f32x4 r = __builtin_elementwise_max(s, zero4); // packed or scalar max
#pragma unroll
        for (int i = 0; i < 4; i++) afrag[kh][hf * 4 + i] = f2bf(r[i]);
      }

#pragma unroll
    for (int nt = 0; nt < 2; nt++) {
      f32x4 cacc = __builtin_amdgcn_mfma_f32_16x16x32_bf16(
          afrag[0], bfrag[nt][0], biasfrag[nt], 0, 0, 0);
      cacc = __builtin_amdgcn_mfma_f32_16x16x32_bf16(
          afrag[1], bfrag[nt][1], cacc, 0, 0, 0);
#pragma unroll
      for (int r = 0; r < 4; r++) accs[nt][r] += fmaxf(cacc[r], 0.f);
    }
  }

  __shared__ float red[JSPLIT][512];
#pragma unroll
  for (int nt = 0; nt < 2; nt++)
#pragma unroll
    for (int r = 0; r < 4; r++)
      red[w][(4 * g + r) * 32 + nt * 16 + ml] = accs[nt][r];
  __syncthreads();
  float sum = 0.f;
#pragma unroll
  for (int ww = 0; ww < JSPLIT; ww++) sum += red[ww][t];
  sum *= (1.0f / (float)KK);
  red[0][t] = sum;
  __syncthreads();

  if (t < 256) {
    int m = t >> 4, dc = t & 15;
    float o = mb3[dc];
#pragma unroll
    for (int n = 0; n < 32; n++) o += red[0][m * 32 + n] * mw3[n * 16 + dc];
    out[(bs_base + m) * 16 + dc] = o;
  }
}

extern "C" void kernel_launch(void* const* d_in, const int* in_sizes, int n_in,
                              void* d_out, int out_size, void* d_ws, size_t ws_size,
                              hipStream_t stream) {
  const float* full = (const float*)d_in[0];
  const float* sw1  = (const float*)d_in[1];
  const float* sb1  = (const float*)d_in[2];
  const float* sw2  = (const float*)d_in[3];
  const float* sb2  = (const float*)d_in[4];
  const float* mw1  = (const float*)d_in[5];
  const float* mb1  = (const float*)d_in[6];
  const float* mw2  = (const float*)d_in[7];
  const float* mb2  = (const float*)d_in[8];
  const float* mw3  = (const float*)d_in[9];
  const float* mb3  = (const float*)d_in[10];
  float* out = (float*)d_out;

  float* ws = (float*)d_ws;
  float* scores = ws;                        // 8192
  float* qpart  = scores + BB * SS;          // 524288
  float* kvb    = qpart + BB * SS * 64;      // 52224

  score_q_kernel<<<(BB * SS) / 256, 256, 0, stream>>>(full, sw1, sb1, sw2, sb2,
                                                      mw1, scores, qpart);
  topk_kvb_kernel<<<BB, 256, 0, stream>>>(scores, full, mw1, mb1, kvb);
  main_mfma_kernel<<<BB * SS / 16, 512, 0, stream>>>(qpart, kvb, mw2, mb2, mw3,
                                                     mb3, out);
}

// Round 5
// 46.478 us; speedup vs baseline: 1.0673x; 1.0673x over previous
//
#include <hip/hip_runtime.h>
#include <hip/hip_bf16.h>

#define BB 4
#define SS 2048
#define DD 16
#define KK 204      // max(1, int(2048*0.1))
#define JSPLIT 8

typedef __attribute__((ext_vector_type(8))) short short8;
typedef __attribute__((ext_vector_type(4))) float f32x4;

__device__ inline short f2bf(float x) {
  __hip_bfloat16 b = __float2bfloat16(x);
  return *reinterpret_cast<short*>(&b);
}

// ---------------- Kernel A: scores + q_part ----------------
__global__ void __launch_bounds__(256) score_q_kernel(
    const float* __restrict__ full, const float* __restrict__ sw1,
    const float* __restrict__ sb1, const float* __restrict__ sw2,
    const float* __restrict__ sb2, const float* __restrict__ mw1,
    float* __restrict__ scores, float* __restrict__ qpart) {
  int idx = blockIdx.x * blockDim.x + threadIdx.x;  // b*SS + s
  if (idx >= BB * SS) return;
  float x[16];
  const float* xp = full + idx * DD;
#pragma unroll
  for (int i = 0; i < 16; i++) x[i] = xp[i];

  float sc = sb2[0];
#pragma unroll
  for (int n = 0; n < 32; n++) {
    float a = sb1[n];
#pragma unroll
    for (int k = 0; k < 16; k++) a += x[k] * sw1[k * 32 + n];
    a = fmaxf(a, 0.f);
    sc += a * sw2[n];
  }
  scores[idx] = sc;

#pragma unroll
  for (int n = 0; n < 64; n++) {
    float a = 0.f;
#pragma unroll
    for (int k = 0; k < 16; k++) a += x[k] * mw1[k * 64 + n];  // w_q = mw1[:16]
    qpart[idx * 64 + n] = a;
  }
}

// ---- Kernel B: fused per-batch top-204 radix select + kvb compute ----
// key = monotone(score)<<11 | (2047-i): larger key = larger value, then
// smaller index; unique keys -> "key >= K*" selects exactly KK items,
// identical semantics to jax top_k. 4 passes of 11 bits (44 >= 43 key bits).
// After selection: cooperative LDS gather of the 204 selected rows (latency
// overlapped across 13 independent loads/thread), then kvb from LDS with
// wsum = wk+wv held in registers.
__global__ void __launch_bounds__(256) topk_kvb_kernel(
    const float* __restrict__ scores, const float* __restrict__ full,
    const float* __restrict__ mw1, const float* __restrict__ mb1,
    float* __restrict__ kvb) {
  int b = blockIdx.x;
  int t = threadIdx.x;
  int lane = t & 63, w = t >> 6;

  __shared__ int hist[2048];       // 8 KB
  __shared__ int wtot[4];
  __shared__ unsigned long long s_pfx;
  __shared__ int s_r;
  __shared__ int s_idx[KK];
  __shared__ float s_x[KK * DD];   // selected rows, ~12.75 KB

  // wsum = wk + wv in registers (loop-invariant for the kvb phase)
  float wreg[16];
#pragma unroll
  for (int k = 0; k < 16; k++)
    wreg[k] = mw1[(16 + k) * 64 + lane] + mw1[(32 + k) * 64 + lane];
  float biasv = mb1[lane];

  unsigned long long key[8];
#pragma unroll
  for (int e = 0; e < 8; e++) {
    int i = t + e * 256;
    float f = scores[b * SS + i];
    unsigned u = __float_as_uint(f);
    u = (u & 0x80000000u) ? ~u : (u | 0x80000000u);  // order-preserving asc
    key[e] = ((unsigned long long)u << 11) | (unsigned)(SS - 1 - i);
  }
  if (t == 0) { s_pfx = 0ull; s_r = KK; }

#pragma unroll
  for (int pass = 0; pass < 4; pass++) {
    int s = 33 - pass * 11;
#pragma unroll
    for (int z = 0; z < 8; z++) hist[t + z * 256] = 0;
    __syncthreads();                       // hist zeroed; s_pfx/s_r visible
    unsigned long long pfx = s_pfx;
    int r = s_r;
#pragma unroll
    for (int e = 0; e < 8; e++) {
      if ((key[e] >> (s + 11)) == pfx)
        atomicAdd(&hist[(int)((key[e] >> s) & 0x7FF)], 1);
    }
    __syncthreads();
    // thread owns bins t*8 .. t*8+7; ls[i] = suffix sum within the 8
    int loc[8], ls[9];
#pragma unroll
    for (int i = 0; i < 8; i++) loc[i] = hist[t * 8 + i];
    ls[8] = 0;
#pragma unroll
    for (int i = 7; i >= 0; i--) ls[i] = ls[i + 1] + loc[i];
    int tot = ls[0];
    // wave inclusive suffix-scan of tot
    int incl = tot;
#pragma unroll
    for (int off = 1; off < 64; off <<= 1) {
      int o = __shfl_down(incl, off);
      incl += (lane + off < 64) ? o : 0;
    }
    if (lane == 0) wtot[w] = incl;  // wave total
    __syncthreads();
    int waveoff = 0;
    for (int ww = w + 1; ww < 4; ww++) waveoff += wtot[ww];
    int excl_thread = waveoff + (incl - tot);  // sum over threads > t
#pragma unroll
    for (int i = 0; i < 8; i++) {
      int sufs = ls[i] + excl_thread;
      int sufn = ls[i + 1] + excl_thread;
      if (sufs >= r && sufn < r) {          // exactly one (thread,bin) matches
        s_pfx = (pfx << 11) | (unsigned)(t * 8 + i);
        s_r = r - sufn;
      }
    }
    __syncthreads();
  }

  unsigned long long kstar = s_pfx;  // full 43-bit key of rank-KK item
  // deterministic compaction: write order sorted by (t, e)
  bool selm[8];
  int c = 0;
#pragma unroll
  for (int e = 0; e < 8; e++) {
    selm[e] = (key[e] >= kstar);
    c += selm[e] ? 1 : 0;
  }
  int p = c;  // wave inclusive prefix
#pragma unroll
  for (int off = 1; off < 64; off <<= 1) {
    int o = __shfl_up(p, off);
    p += (lane >= off) ? o : 0;
  }
  if (lane == 63) wtot[w] = p;
  __syncthreads();
  int base = 0;
  for (int ww = 0; ww < w; ww++) base += wtot[ww];
  int pos = base + p - c;
#pragma unroll
  for (int e = 0; e < 8; e++) {
    if (selm[e]) s_idx[pos++] = t + e * 256;
  }
  __syncthreads();

  // cooperative gather of selected rows into LDS (independent loads -> overlap)
  for (int i = t; i < KK * DD; i += 256) {
    int j = i >> 4, e = i & 15;
    s_x[i] = full[(b * SS + s_idx[j]) * DD + e];
  }
  __syncthreads();

  // kvb: wave w handles j = w, w+4, ... ; x row is broadcast LDS read
  for (int j = w; j < KK; j += 4) {
    const float* xr = &s_x[j * DD];
    float a = biasv;
#pragma unroll
    for (int k = 0; k < 16; k++) a += xr[k] * wreg[k];
    kvb[(b * KK + j) * 64 + lane] = a;
  }
}

// ---------------- Kernel D: main (MFMA bf16) ----------------
// Block = 8 waves, one m-tile of 16 (b,s) rows; wave w handles 26 j's.
// A frag (16x16x32 bf16): lane l holds A[m=l&15][k=8*(l>>4)+i], i=0..7.
// B frag:                 lane l holds B[k=8*(l>>4)+i][n=l&15].
// D frag (m89-verified):  lane l, reg r -> D[m=4*(l>>4)+r][n=l&15].
__global__ void __launch_bounds__(512) main_mfma_kernel(
    const float* __restrict__ qpart, const float* __restrict__ kvb,
    const float* __restrict__ mw2, const float* __restrict__ mb2,
    const float* __restrict__ mw3, const float* __restrict__ mb3,
    float* __restrict__ out) {
  int mtile = blockIdx.x;            // 0..511
  int bs_base = mtile * 16;
  int b = bs_base >> 11;
  int t = threadIdx.x;
  int w = t >> 6;
  int l = t & 63;
  int ml = l & 15;
  int g = l >> 4;

  f32x4 qv[2][2];
  {
    const float* qp = qpart + (bs_base + ml) * 64 + 8 * g;
    qv[0][0] = *(const f32x4*)(qp);
    qv[0][1] = *(const f32x4*)(qp + 4);
    qv[1][0] = *(const f32x4*)(qp + 32);
    qv[1][1] = *(const f32x4*)(qp + 36);
  }

  short8 bfrag[2][2];  // [ntile][khalf]
#pragma unroll
  for (int nt = 0; nt < 2; nt++)
#pragma unroll
    for (int kh = 0; kh < 2; kh++)
#pragma unroll
      for (int i = 0; i < 8; i++) {
        int k = kh * 32 + 8 * g + i;
        bfrag[nt][kh][i] = f2bf(mw2[k * 32 + nt * 16 + ml]);
      }

  f32x4 biasfrag[2];
#pragma unroll
  for (int nt = 0; nt < 2; nt++) {
    float bv = mb2[nt * 16 + ml];
    f32x4 bf;
    bf[0] = bv; bf[1] = bv; bf[2] = bv; bf[3] = bv;
    biasfrag[nt] = bf;
  }

  float accs[2][4] = {};
  int jbeg = w * 26;
  int jend = jbeg + 26;
  if (jend > KK) jend = KK;
  const float* kvbb = kvb + b * KK * 64 + 8 * g;

#pragma unroll 2
  for (int j = jbeg; j < jend; j++) {
    const float* kp = kvbb + j * 64;
    f32x4 kv[2][2];
    kv[0][0] = *(const f32x4*)(kp);
    kv[0][1] = *(const f32x4*)(kp + 4);
    kv[1][0] = *(const f32x4*)(kp + 32);
    kv[1][1] = *(const f32x4*)(kp + 36);

    short8 afrag[2];
#pragma unroll
    for (int kh = 0; kh < 2; kh++)
#pragma unroll
      for (int hf = 0; hf < 2; hf++)
#pragma unroll
        for (int i = 0; i < 4; i++) {
          float h = fmaxf(qv[kh][hf][i] + kv[kh][hf][i], 0.f);
          afrag[kh][hf * 4 + i] = f2bf(h);
        }

#pragma unroll
    for (int nt = 0; nt < 2; nt++) {
      f32x4 c = __builtin_amdgcn_mfma_f32_16x16x32_bf16(
          afrag[0], bfrag[nt][0], biasfrag[nt], 0, 0, 0);
      c = __builtin_amdgcn_mfma_f32_16x16x32_bf16(
          afrag[1], bfrag[nt][1], c, 0, 0, 0);
#pragma unroll
      for (int r = 0; r < 4; r++) accs[nt][r] += fmaxf(c[r], 0.f);
    }
  }

  __shared__ float red[JSPLIT][512];
#pragma unroll
  for (int nt = 0; nt < 2; nt++)
#pragma unroll
    for (int r = 0; r < 4; r++)
      red[w][(4 * g + r) * 32 + nt * 16 + ml] = accs[nt][r];
  __syncthreads();
  float sum = 0.f;
#pragma unroll
  for (int ww = 0; ww < JSPLIT; ww++) sum += red[ww][t];
  sum *= (1.0f / (float)KK);
  red[0][t] = sum;
  __syncthreads();

  if (t < 256) {
    int m = t >> 4, dc = t & 15;
    float o = mb3[dc];
#pragma unroll
    for (int n = 0; n < 32; n++) o += red[0][m * 32 + n] * mw3[n * 16 + dc];
    out[(bs_base + m) * 16 + dc] = o;
  }
}

extern "C" void kernel_launch(void* const* d_in, const int* in_sizes, int n_in,
                              void* d_out, int out_size, void* d_ws, size_t ws_size,
                              hipStream_t stream) {
  const float* full = (const float*)d_in[0];
  const float* sw1  = (const float*)d_in[1];
  const float* sb1  = (const float*)d_in[2];
  const float* sw2  = (const float*)d_in[3];
  const float* sb2  = (const float*)d_in[4];
  const float* mw1  = (const float*)d_in[5];
  const float* mb1  = (const float*)d_in[6];
  const float* mw2  = (const float*)d_in[7];
  const float* mb2  = (const float*)d_in[8];
  const float* mw3  = (const float*)d_in[9];
  const float* mb3  = (const float*)d_in[10];
  float* out = (float*)d_out;

  float* ws = (float*)d_ws;
  float* scores = ws;                        // 8192
  float* qpart  = scores + BB * SS;          // 524288
  float* kvb    = qpart + BB * SS * 64;      // 52224

  score_q_kernel<<<(BB * SS) / 256, 256, 0, stream>>>(full, sw1, sb1, sw2, sb2,
                                                      mw1, scores, qpart);
  topk_kvb_kernel<<<BB, 256, 0, stream>>>(scores, full, mw1, mb1, kvb);
  main_mfma_kernel<<<BB * SS / 16, 512, 0, stream>>>(qpart, kvb, mw2, mb2, mw3,
                                                     mb3, out);
}

// Round 6
// 44.697 us; speedup vs baseline: 1.1098x; 1.0399x over previous
//
#include <hip/hip_runtime.h>
#include <hip/hip_bf16.h>

#define BB 4
#define SS 2048
#define DD 16
#define KK 204      // max(1, int(2048*0.1))
#define JSPLIT 8

typedef __attribute__((ext_vector_type(8))) short short8;
typedef __attribute__((ext_vector_type(4))) float f32x4;

__device__ inline short f2bf(float x) {
  __hip_bfloat16 b = __float2bfloat16(x);
  return *reinterpret_cast<short*>(&b);
}

// ---------------- Kernel A: scores + q_part ----------------
__global__ void __launch_bounds__(256) score_q_kernel(
    const float* __restrict__ full, const float* __restrict__ sw1,
    const float* __restrict__ sb1, const float* __restrict__ sw2,
    const float* __restrict__ sb2, const float* __restrict__ mw1,
    float* __restrict__ scores, float* __restrict__ qpart) {
  int idx = blockIdx.x * blockDim.x + threadIdx.x;  // b*SS + s
  if (idx >= BB * SS) return;
  float x[16];
  const float* xp = full + idx * DD;
#pragma unroll
  for (int i = 0; i < 16; i++) x[i] = xp[i];

  float sc = sb2[0];
#pragma unroll
  for (int n = 0; n < 32; n++) {
    float a = sb1[n];
#pragma unroll
    for (int k = 0; k < 16; k++) a += x[k] * sw1[k * 32 + n];
    a = fmaxf(a, 0.f);
    sc += a * sw2[n];
  }
  scores[idx] = sc;

#pragma unroll
  for (int n = 0; n < 64; n++) {
    float a = 0.f;
#pragma unroll
    for (int k = 0; k < 16; k++) a += x[k] * mw1[k * 64 + n];  // w_q = mw1[:16]
    qpart[idx * 64 + n] = a;
  }
}

// ---- Kernel B: fused per-batch top-204 radix select + kvb compute ----
// key = monotone(score)<<11 | (2047-i): larger key = larger value, then
// smaller index; unique keys -> "key >= K*" selects exactly KK items,
// identical semantics to jax top_k. 4 passes of 11 bits (44 >= 43 key bits).
__global__ void __launch_bounds__(256) topk_kvb_kernel(
    const float* __restrict__ scores, const float* __restrict__ full,
    const float* __restrict__ mw1, const float* __restrict__ mb1,
    float* __restrict__ kvb) {
  int b = blockIdx.x;
  int t = threadIdx.x;
  int lane = t & 63, w = t >> 6;

  __shared__ int hist[2048];       // 8 KB
  __shared__ int wtot[4];
  __shared__ unsigned long long s_pfx;
  __shared__ int s_r;
  __shared__ int s_idx[KK];
  __shared__ float s_x[KK * DD];   // selected rows, ~12.75 KB

  // wsum = wk + wv in registers (loop-invariant for the kvb phase)
  float wreg[16];
#pragma unroll
  for (int k = 0; k < 16; k++)
    wreg[k] = mw1[(16 + k) * 64 + lane] + mw1[(32 + k) * 64 + lane];
  float biasv = mb1[lane];

  unsigned long long key[8];
#pragma unroll
  for (int e = 0; e < 8; e++) {
    int i = t + e * 256;
    float f = scores[b * SS + i];
    unsigned u = __float_as_uint(f);
    u = (u & 0x80000000u) ? ~u : (u | 0x80000000u);  // order-preserving asc
    key[e] = ((unsigned long long)u << 11) | (unsigned)(SS - 1 - i);
  }
  if (t == 0) { s_pfx = 0ull; s_r = KK; }

#pragma unroll
  for (int pass = 0; pass < 4; pass++) {
    int s = 33 - pass * 11;
#pragma unroll
    for (int z = 0; z < 8; z++) hist[t + z * 256] = 0;
    __syncthreads();                       // hist zeroed; s_pfx/s_r visible
    unsigned long long pfx = s_pfx;
    int r = s_r;
#pragma unroll
    for (int e = 0; e < 8; e++) {
      if ((key[e] >> (s + 11)) == pfx)
        atomicAdd(&hist[(int)((key[e] >> s) & 0x7FF)], 1);
    }
    __syncthreads();
    // thread owns bins t*8 .. t*8+7; ls[i] = suffix sum within the 8
    int loc[8], ls[9];
#pragma unroll
    for (int i = 0; i < 8; i++) loc[i] = hist[t * 8 + i];
    ls[8] = 0;
#pragma unroll
    for (int i = 7; i >= 0; i--) ls[i] = ls[i + 1] + loc[i];
    int tot = ls[0];
    // wave inclusive suffix-scan of tot
    int incl = tot;
#pragma unroll
    for (int off = 1; off < 64; off <<= 1) {
      int o = __shfl_down(incl, off);
      incl += (lane + off < 64) ? o : 0;
    }
    if (lane == 0) wtot[w] = incl;  // wave total
    __syncthreads();
    int waveoff = 0;
    for (int ww = w + 1; ww < 4; ww++) waveoff += wtot[ww];
    int excl_thread = waveoff + (incl - tot);  // sum over threads > t
#pragma unroll
    for (int i = 0; i < 8; i++) {
      int sufs = ls[i] + excl_thread;
      int sufn = ls[i + 1] + excl_thread;
      if (sufs >= r && sufn < r) {          // exactly one (thread,bin) matches
        s_pfx = (pfx << 11) | (unsigned)(t * 8 + i);
        s_r = r - sufn;
      }
    }
    __syncthreads();
  }

  unsigned long long kstar = s_pfx;  // full 43-bit key of rank-KK item
  // deterministic compaction: write order sorted by (t, e)
  bool selm[8];
  int c = 0;
#pragma unroll
  for (int e = 0; e < 8; e++) {
    selm[e] = (key[e] >= kstar);
    c += selm[e] ? 1 : 0;
  }
  int p = c;  // wave inclusive prefix
#pragma unroll
  for (int off = 1; off < 64; off <<= 1) {
    int o = __shfl_up(p, off);
    p += (lane >= off) ? o : 0;
  }
  if (lane == 63) wtot[w] = p;
  __syncthreads();
  int base = 0;
  for (int ww = 0; ww < w; ww++) base += wtot[ww];
  int pos = base + p - c;
#pragma unroll
  for (int e = 0; e < 8; e++) {
    if (selm[e]) s_idx[pos++] = t + e * 256;
  }
  __syncthreads();

  // cooperative gather of selected rows into LDS (independent loads -> overlap)
  for (int i = t; i < KK * DD; i += 256) {
    int j = i >> 4, e = i & 15;
    s_x[i] = full[(b * SS + s_idx[j]) * DD + e];
  }
  __syncthreads();

  // kvb: wave w handles j = w, w+4, ... ; x row is broadcast LDS read
  for (int j = w; j < KK; j += 4) {
    const float* xr = &s_x[j * DD];
    float a = biasv;
#pragma unroll
    for (int k = 0; k < 16; k++) a += xr[k] * wreg[k];
    kvb[(b * KK + j) * 64 + lane] = a;
  }
}

// ---------------- Kernel D: main (MFMA bf16, LDS-staged kvb) ----------------
// Block = 8 waves, one m-tile of 16 (b,s) rows; wave w handles 26 j's.
// kvb[b] (52 KB) is staged into LDS once (it is re-read 26x per block; global
// reads were cross-XCD L2/L3 latency-bound). j-loop reads are broadcast
// ds_read_b128 (16 lanes same address, conflict-free).
// A frag (16x16x32 bf16): lane l holds A[m=l&15][k=8*(l>>4)+i], i=0..7.
// B frag:                 lane l holds B[k=8*(l>>4)+i][n=l&15].
// D frag (m89-verified):  lane l, reg r -> D[m=4*(l>>4)+r][n=l&15].
__global__ void __launch_bounds__(512) main_mfma_kernel(
    const float* __restrict__ qpart, const float* __restrict__ kvb,
    const float* __restrict__ mw2, const float* __restrict__ mb2,
    const float* __restrict__ mw3, const float* __restrict__ mb3,
    float* __restrict__ out) {
  int mtile = blockIdx.x;            // 0..511
  int bs_base = mtile * 16;
  int b = bs_base >> 11;
  int t = threadIdx.x;
  int w = t >> 6;
  int l = t & 63;
  int ml = l & 15;
  int g = l >> 4;

  __shared__ float s_kvb[KK * 64];   // 52224 B; aliased as `red` after j-loop
  float (*red)[512] = (float(*)[512])s_kvb;

  // stage kvb[b] into LDS (coalesced f32x4, 7 independent loads/thread)
  {
    const f32x4* src = (const f32x4*)(kvb + b * KK * 64);
    f32x4* dst = (f32x4*)s_kvb;
    for (int i = t; i < KK * 16; i += 512) dst[i] = src[i];
  }

  f32x4 qv[2][2];
  {
    const float* qp = qpart + (bs_base + ml) * 64 + 8 * g;
    qv[0][0] = *(const f32x4*)(qp);
    qv[0][1] = *(const f32x4*)(qp + 4);
    qv[1][0] = *(const f32x4*)(qp + 32);
    qv[1][1] = *(const f32x4*)(qp + 36);
  }

  short8 bfrag[2][2];  // [ntile][khalf]
#pragma unroll
  for (int nt = 0; nt < 2; nt++)
#pragma unroll
    for (int kh = 0; kh < 2; kh++)
#pragma unroll
      for (int i = 0; i < 8; i++) {
        int k = kh * 32 + 8 * g + i;
        bfrag[nt][kh][i] = f2bf(mw2[k * 32 + nt * 16 + ml]);
      }

  f32x4 biasfrag[2];
#pragma unroll
  for (int nt = 0; nt < 2; nt++) {
    float bv = mb2[nt * 16 + ml];
    f32x4 bf;
    bf[0] = bv; bf[1] = bv; bf[2] = bv; bf[3] = bv;
    biasfrag[nt] = bf;
  }

  float accs[2][4] = {};
  int jbeg = w * 26;
  int jend = jbeg + 26;
  if (jend > KK) jend = KK;

  __syncthreads();  // s_kvb staged

  const float* kvbl = s_kvb + 8 * g;
#pragma unroll 2
  for (int j = jbeg; j < jend; j++) {
    const float* kp = kvbl + j * 64;
    f32x4 kv[2][2];
    kv[0][0] = *(const f32x4*)(kp);
    kv[0][1] = *(const f32x4*)(kp + 4);
    kv[1][0] = *(const f32x4*)(kp + 32);
    kv[1][1] = *(const f32x4*)(kp + 36);

    short8 afrag[2];
#pragma unroll
    for (int kh = 0; kh < 2; kh++)
#pragma unroll
      for (int hf = 0; hf < 2; hf++)
#pragma unroll
        for (int i = 0; i < 4; i++) {
          float h = fmaxf(qv[kh][hf][i] + kv[kh][hf][i], 0.f);
          afrag[kh][hf * 4 + i] = f2bf(h);
        }

#pragma unroll
    for (int nt = 0; nt < 2; nt++) {
      f32x4 c = __builtin_amdgcn_mfma_f32_16x16x32_bf16(
          afrag[0], bfrag[nt][0], biasfrag[nt], 0, 0, 0);
      c = __builtin_amdgcn_mfma_f32_16x16x32_bf16(
          afrag[1], bfrag[nt][1], c, 0, 0, 0);
#pragma unroll
      for (int r = 0; r < 4; r++) accs[nt][r] += fmaxf(c[r], 0.f);
    }
  }

  __syncthreads();  // all waves done reading s_kvb before aliasing as red
#pragma unroll
  for (int nt = 0; nt < 2; nt++)
#pragma unroll
    for (int r = 0; r < 4; r++)
      red[w][(4 * g + r) * 32 + nt * 16 + ml] = accs[nt][r];
  __syncthreads();
  float sum = 0.f;
#pragma unroll
  for (int ww = 0; ww < JSPLIT; ww++) sum += red[ww][t];
  sum *= (1.0f / (float)KK);
  red[0][t] = sum;
  __syncthreads();

  if (t < 256) {
    int m = t >> 4, dc = t & 15;
    float o = mb3[dc];
#pragma unroll
    for (int n = 0; n < 32; n++) o += red[0][m * 32 + n] * mw3[n * 16 + dc];
    out[(bs_base + m) * 16 + dc] = o;
  }
}

extern "C" void kernel_launch(void* const* d_in, const int* in_sizes, int n_in,
                              void* d_out, int out_size, void* d_ws, size_t ws_size,
                              hipStream_t stream) {
  const float* full = (const float*)d_in[0];
  const float* sw1  = (const float*)d_in[1];
  const float* sb1  = (const float*)d_in[2];
  const float* sw2  = (const float*)d_in[3];
  const float* sb2  = (const float*)d_in[4];
  const float* mw1  = (const float*)d_in[5];
  const float* mb1  = (const float*)d_in[6];
  const float* mw2  = (const float*)d_in[7];
  const float* mb2  = (const float*)d_in[8];
  const float* mw3  = (const float*)d_in[9];
  const float* mb3  = (const float*)d_in[10];
  float* out = (float*)d_out;

  float* ws = (float*)d_ws;
  float* scores = ws;                        // 8192
  float* qpart  = scores + BB * SS;          // 524288
  float* kvb    = qpart + BB * SS * 64;      // 52224

  score_q_kernel<<<(BB * SS) / 256, 256, 0, stream>>>(full, sw1, sb1, sw2, sb2,
                                                      mw1, scores, qpart);
  topk_kvb_kernel<<<BB, 256, 0, stream>>>(scores, full, mw1, mb1, kvb);
  main_mfma_kernel<<<BB * SS / 16, 512, 0, stream>>>(qpart, kvb, mw2, mb2, mw3,
                                                     mb3, out);
}